// Round 2
// baseline (456.883 us; speedup 1.0000x reference)
//
#include <hip/hip_runtime.h>
#include <hip/hip_bf16.h>

#define BATCH 128
#define IN_DIM 512
#define HDIM 1024

typedef __attribute__((ext_vector_type(4))) float f32x4;

// tanh(x) = 1 - 2/(e^{2x}+1); saturates correctly at +-inf
__device__ __forceinline__ float fast_tanh(float x) {
    float e = __expf(2.0f * x);
    return 1.0f - 2.0f * __builtin_amdgcn_rcpf(e + 1.0f);
}

// K1: emb[b,h] = tanh(items[b,:] . W1[h,:] + b1[h]);  grid=B, block=256
__global__ __launch_bounds__(256) void k1_emb(
    const float* __restrict__ items, const float* __restrict__ W1,
    const float* __restrict__ b1, float* __restrict__ emb_f)
{
    __shared__ float it[IN_DIM];
    int b = blockIdx.x, t = threadIdx.x;
    it[t] = items[b * IN_DIM + t];
    it[t + 256] = items[b * IN_DIM + t + 256];
    __syncthreads();
    #pragma unroll
    for (int j = 0; j < 4; ++j) {
        int h = t + 256 * j;
        const float* wrow = W1 + h * IN_DIM;
        float acc = 0.f;
        #pragma unroll 4
        for (int c = 0; c < IN_DIM; c += 4) {
            f32x4 w = *reinterpret_cast<const f32x4*>(wrow + c);
            acc += w[0] * it[c] + w[1] * it[c + 1] + w[2] * it[c + 2] + w[3] * it[c + 3];
        }
        emb_f[b * HDIM + h] = tanhf(acc + b1[h]);
    }
}

// K2: pre[b,h] = b2[h] + sum_i emb[b,i]*(alpha[h,i]*plastic[b,h,i] + W2[h,i])
//     hid[b,h] = tanh(pre).  One wave per (b,h) row. grid=B*H/4, block=256
__global__ __launch_bounds__(256) void k2_hidden(
    const float* __restrict__ plastic, const float* __restrict__ alpha,
    const float* __restrict__ W2, const float* __restrict__ b2,
    const float* __restrict__ emb_f, float* __restrict__ pre_f, float* __restrict__ hid_f)
{
    int bid = blockIdx.x;
    int b = bid >> 8;
    int h = ((bid & 255) << 2) + (threadIdx.x >> 6);
    int l = threadIdx.x & 63;
    const float* prow = plastic + (((size_t)b) << 20) + ((size_t)h << 10);
    const float* arow = alpha + (h << 10);
    const float* wrow = W2 + (h << 10);
    const float* erow = emb_f + (b << 10);
    float acc = 0.f;
    #pragma unroll
    for (int c = 0; c < 4; ++c) {
        int i = c * 256 + l * 4;
        f32x4 p = *reinterpret_cast<const f32x4*>(prow + i);
        f32x4 a = *reinterpret_cast<const f32x4*>(arow + i);
        f32x4 w = *reinterpret_cast<const f32x4*>(wrow + i);
        f32x4 e = *reinterpret_cast<const f32x4*>(erow + i);
        acc += e[0] * fmaf(a[0], p[0], w[0]);
        acc += e[1] * fmaf(a[1], p[1], w[1]);
        acc += e[2] * fmaf(a[2], p[2], w[2]);
        acc += e[3] * fmaf(a[3], p[3], w[3]);
    }
    #pragma unroll
    for (int off = 32; off > 0; off >>= 1) acc += __shfl_xor(acc, off);
    if (l == 0) {
        float pre = acc + b2[h];
        pre_f[(b << 10) + h] = pre;
        hid_f[(b << 10) + h] = tanhf(pre);
    }
}

// K3a: t3[b,h] = tanh( sum_i (hid[b,i] + reward[b]*Wr[i] + br[i]) * W3[h,i] + b3[h] )
__global__ __launch_bounds__(256) void k3a_t3(
    const float* __restrict__ hid_f, const float* __restrict__ reward,
    const float* __restrict__ Wr, const float* __restrict__ br,
    const float* __restrict__ W3, const float* __restrict__ b3,
    float* __restrict__ t3_f)
{
    int bid = blockIdx.x;
    int b = bid >> 8;
    int h = ((bid & 255) << 2) + (threadIdx.x >> 6);
    int l = threadIdx.x & 63;
    float rw = reward[b];
    const float* wrow = W3 + (h << 10);
    const float* hrow = hid_f + (b << 10);
    float acc = 0.f;
    #pragma unroll
    for (int c = 0; c < 4; ++c) {
        int i = c * 256 + l * 4;
        f32x4 w  = *reinterpret_cast<const f32x4*>(wrow + i);
        f32x4 wr = *reinterpret_cast<const f32x4*>(Wr + i);
        f32x4 bb = *reinterpret_cast<const f32x4*>(br + i);
        f32x4 hh = *reinterpret_cast<const f32x4*>(hrow + i);
        #pragma unroll
        for (int j = 0; j < 4; ++j)
            acc += (hh[j] + fmaf(rw, wr[j], bb[j])) * w[j];
    }
    #pragma unroll
    for (int off = 32; off > 0; off >>= 1) acc += __shfl_xor(acc, off);
    if (l == 0) t3_f[(b << 10) + h] = tanhf(acc + b3[h]);
}

// K3b: per-b heads: nm, choice, value; also emit hidden. grid=B, block=256
__global__ __launch_bounds__(256) void k3b_heads(
    const float* __restrict__ t3_f, const float* __restrict__ hid_f,
    const float* __restrict__ Wn, const float* __restrict__ bn,
    const float* __restrict__ Wc, const float* __restrict__ bc,
    const float* __restrict__ Wv, const float* __restrict__ bv,
    float* __restrict__ nm_f, float* __restrict__ out)
{
    int b = blockIdx.x, t = threadIdx.x;
    int w = t >> 6, l = t & 63;
    const float* src = (w < 2) ? (t3_f + (b << 10)) : (hid_f + (b << 10));
    const float* wv = (w == 0) ? Wn : (w == 1) ? (Wn + HDIM) : (w == 2) ? Wc : Wv;
    float acc = 0.f;
    #pragma unroll
    for (int c = 0; c < 4; ++c) {
        int i = c * 256 + l * 4;
        f32x4 wg = *reinterpret_cast<const f32x4*>(wv + i);
        f32x4 ss = *reinterpret_cast<const f32x4*>(src + i);
        acc += ss[0] * wg[0] + ss[1] * wg[1] + ss[2] * wg[2] + ss[3] * wg[3];
    }
    #pragma unroll
    for (int off = 32; off > 0; off >>= 1) acc += __shfl_xor(acc, off);
    __shared__ float red[4];
    if (l == 0) red[w] = acc;
    __syncthreads();
    if (t == 0) {
        float nm0 = tanhf(red[0] + bn[0]);
        float nm1 = tanhf(red[1] + bn[1]);
        float nm = nm0 - nm1;
        nm_f[b] = nm;
        out[BATCH + b] = nm;                                  // neuromodulator
        out[b] = 1.0f / (1.0f + __expf(-(red[2] + bc[0])));   // choice
        out[2 * BATCH + b] = red[3] + bv[0];                  // value
    }
    const size_t HID_OFF = (size_t)3 * BATCH + (size_t)BATCH * HDIM * HDIM;
    for (int i = t; i < HDIM; i += 256)
        out[HID_OFF + (size_t)b * HDIM + i] = hid_f[(b << 10) + i];
}

// K4: new_plastic = clip(plastic + nm[b]*tanh(pre[b,h]*emb[b,i])*10, -50, 50)
// grid = B*H*H/1024, block=256, 4 elems (one f32x4) per thread
__global__ __launch_bounds__(256) void k4_update(
    const float* __restrict__ plastic, const float* __restrict__ emb_f,
    const float* __restrict__ pre_f, const float* __restrict__ nm_f,
    float* __restrict__ outp)
{
    size_t idx = ((size_t)blockIdx.x * 256 + threadIdx.x) * 4;
    int b   = (int)(idx >> 20);
    int rem = (int)(idx & 1048575u);
    int h   = rem >> 10;
    int i0  = rem & 1023;
    float nm  = nm_f[b];
    float pre = pre_f[(b << 10) + h];
    f32x4 p = *reinterpret_cast<const f32x4*>(plastic + idx);
    f32x4 e = *reinterpret_cast<const f32x4*>(emb_f + (b << 10) + i0);
    f32x4 o;
    #pragma unroll
    for (int j = 0; j < 4; ++j) {
        float heb = fast_tanh(pre * e[j]) * 10.0f;
        float v = fmaf(nm, heb, p[j]);
        o[j] = fminf(fmaxf(v, -50.0f), 50.0f);
    }
    *reinterpret_cast<f32x4*>(outp + idx) = o;
}

extern "C" void kernel_launch(void* const* d_in, const int* in_sizes, int n_in,
                              void* d_out, int out_size, void* d_ws, size_t ws_size,
                              hipStream_t stream)
{
    const float* items   = (const float*)d_in[0];
    const float* plastic = (const float*)d_in[1];
    const float* reward  = (const float*)d_in[2];
    const float* W1 = (const float*)d_in[3];
    const float* b1 = (const float*)d_in[4];
    const float* W2 = (const float*)d_in[5];
    const float* b2 = (const float*)d_in[6];
    const float* W3 = (const float*)d_in[7];
    const float* b3 = (const float*)d_in[8];
    const float* Wc = (const float*)d_in[9];
    const float* bc = (const float*)d_in[10];
    const float* Wr = (const float*)d_in[11];
    const float* br = (const float*)d_in[12];
    const float* Wn = (const float*)d_in[13];
    const float* bn = (const float*)d_in[14];
    const float* alpha = (const float*)d_in[15];
    const float* Wv = (const float*)d_in[16];
    const float* bv = (const float*)d_in[17];

    float* ws    = (float*)d_ws;
    float* emb_f = ws;                // 131072 floats
    float* pre_f = ws + 131072;       // 131072
    float* hid_f = ws + 262144;       // 131072
    float* t3_f  = ws + 393216;       // 131072
    float* nm_f  = ws + 524288;       // 128

    float* out  = (float*)d_out;
    float* outp = out + 384;          // new_plastic after choice/nm/value

    k1_emb   <<<BATCH, 256, 0, stream>>>(items, W1, b1, emb_f);
    k2_hidden<<<(BATCH * HDIM) / 4, 256, 0, stream>>>(plastic, alpha, W2, b2, emb_f, pre_f, hid_f);
    k3a_t3   <<<(BATCH * HDIM) / 4, 256, 0, stream>>>(hid_f, reward, Wr, br, W3, b3, t3_f);
    k3b_heads<<<BATCH, 256, 0, stream>>>(t3_f, hid_f, Wn, bn, Wc, bc, Wv, bv, nm_f, out);
    k4_update<<<(size_t)(BATCH * HDIM) * HDIM / 1024, 256, 0, stream>>>(plastic, emb_f, pre_f, nm_f, outp);
}

// Round 3
// 406.724 us; speedup vs baseline: 1.1233x; 1.1233x over previous
//
#include <hip/hip_runtime.h>
#include <hip/hip_bf16.h>

#define BATCH 128
#define IN_DIM 512
#define HDIM 1024
#define BCHUNK 8

typedef __attribute__((ext_vector_type(4))) float f32x4;

// tanh(x) = 1 - 2/(e^{2x}+1); saturates correctly at +-inf
__device__ __forceinline__ float fast_tanh(float x) {
    float e = __expf(2.0f * x);
    return 1.0f - 2.0f * __builtin_amdgcn_rcpf(e + 1.0f);
}

// K1: emb[b,h] = tanh(items[b,:] . W1[h,:] + b1[h]);  grid=B, block=256
__global__ __launch_bounds__(256) void k1_emb(
    const float* __restrict__ items, const float* __restrict__ W1,
    const float* __restrict__ b1, float* __restrict__ emb_f)
{
    __shared__ float it[IN_DIM];
    int b = blockIdx.x, t = threadIdx.x;
    it[t] = items[b * IN_DIM + t];
    it[t + 256] = items[b * IN_DIM + t + 256];
    __syncthreads();
    #pragma unroll
    for (int j = 0; j < 4; ++j) {
        int h = t + 256 * j;
        const float* wrow = W1 + h * IN_DIM;
        float acc = 0.f;
        #pragma unroll 4
        for (int c = 0; c < IN_DIM; c += 4) {
            f32x4 w = *reinterpret_cast<const f32x4*>(wrow + c);
            acc += w[0] * it[c] + w[1] * it[c + 1] + w[2] * it[c + 2] + w[3] * it[c + 3];
        }
        emb_f[b * HDIM + h] = tanhf(acc + b1[h]);
    }
}

// K2: pre[b,h] = b2[h] + sum_i emb[b,i]*(alpha[h,i]*plastic[b,h,i] + W2[h,i])
//     hid[b,h] = tanh(pre).
// Block = 4 waves; wave w owns row h = hg*4+w, caches alpha/W2 rows in REGISTERS,
// loops over an 8-batch chunk. grid = (H/4) * (B/BCHUNK) = 256*16 = 4096.
__global__ __launch_bounds__(256) void k2_hidden(
    const float* __restrict__ plastic, const float* __restrict__ alpha,
    const float* __restrict__ W2, const float* __restrict__ b2,
    const float* __restrict__ emb_f, float* __restrict__ pre_f, float* __restrict__ hid_f)
{
    int hg = blockIdx.x & 255;
    int bc = blockIdx.x >> 8;
    int w  = threadIdx.x >> 6;
    int l  = threadIdx.x & 63;
    int h  = (hg << 2) + w;

    const float* arow = alpha + (h << 10);
    const float* wrow = W2 + (h << 10);
    f32x4 ar[4], wr[4];
    #pragma unroll
    for (int c = 0; c < 4; ++c) {
        int i = c * 256 + l * 4;
        ar[c] = *reinterpret_cast<const f32x4*>(arow + i);
        wr[c] = *reinterpret_cast<const f32x4*>(wrow + i);
    }
    float b2h = b2[h];

    #pragma unroll 2
    for (int bb = 0; bb < BCHUNK; ++bb) {
        int b = bc * BCHUNK + bb;
        const float* prow = plastic + (((size_t)b) << 20) + ((size_t)h << 10);
        const float* erow = emb_f + (b << 10);
        float acc = 0.f;
        #pragma unroll
        for (int c = 0; c < 4; ++c) {
            int i = c * 256 + l * 4;
            f32x4 p = *reinterpret_cast<const f32x4*>(prow + i);
            f32x4 e = *reinterpret_cast<const f32x4*>(erow + i);
            acc += e[0] * fmaf(ar[c][0], p[0], wr[c][0]);
            acc += e[1] * fmaf(ar[c][1], p[1], wr[c][1]);
            acc += e[2] * fmaf(ar[c][2], p[2], wr[c][2]);
            acc += e[3] * fmaf(ar[c][3], p[3], wr[c][3]);
        }
        #pragma unroll
        for (int off = 32; off > 0; off >>= 1) acc += __shfl_xor(acc, off);
        if (l == 0) {
            float pre = acc + b2h;
            pre_f[(b << 10) + h] = pre;
            hid_f[(b << 10) + h] = tanhf(pre);
        }
    }
}

// K3a: t3[b,h] = tanh( sum_i (hid[b,i] + reward[b]*Wr[i] + br[i]) * W3[h,i] + b3[h] )
__global__ __launch_bounds__(256) void k3a_t3(
    const float* __restrict__ hid_f, const float* __restrict__ reward,
    const float* __restrict__ Wr, const float* __restrict__ br,
    const float* __restrict__ W3, const float* __restrict__ b3,
    float* __restrict__ t3_f)
{
    int bid = blockIdx.x;
    int b = bid >> 8;
    int h = ((bid & 255) << 2) + (threadIdx.x >> 6);
    int l = threadIdx.x & 63;
    float rw = reward[b];
    const float* wrow = W3 + (h << 10);
    const float* hrow = hid_f + (b << 10);
    float acc = 0.f;
    #pragma unroll
    for (int c = 0; c < 4; ++c) {
        int i = c * 256 + l * 4;
        f32x4 w  = *reinterpret_cast<const f32x4*>(wrow + i);
        f32x4 wr = *reinterpret_cast<const f32x4*>(Wr + i);
        f32x4 bb = *reinterpret_cast<const f32x4*>(br + i);
        f32x4 hh = *reinterpret_cast<const f32x4*>(hrow + i);
        #pragma unroll
        for (int j = 0; j < 4; ++j)
            acc += (hh[j] + fmaf(rw, wr[j], bb[j])) * w[j];
    }
    #pragma unroll
    for (int off = 32; off > 0; off >>= 1) acc += __shfl_xor(acc, off);
    if (l == 0) t3_f[(b << 10) + h] = tanhf(acc + b3[h]);
}

// K3b: per-b heads: nm, choice, value; also emit hidden. grid=B, block=256
__global__ __launch_bounds__(256) void k3b_heads(
    const float* __restrict__ t3_f, const float* __restrict__ hid_f,
    const float* __restrict__ Wn, const float* __restrict__ bn,
    const float* __restrict__ Wc, const float* __restrict__ bc,
    const float* __restrict__ Wv, const float* __restrict__ bv,
    float* __restrict__ nm_f, float* __restrict__ out)
{
    int b = blockIdx.x, t = threadIdx.x;
    int w = t >> 6, l = t & 63;
    const float* src = (w < 2) ? (t3_f + (b << 10)) : (hid_f + (b << 10));
    const float* wv = (w == 0) ? Wn : (w == 1) ? (Wn + HDIM) : (w == 2) ? Wc : Wv;
    float acc = 0.f;
    #pragma unroll
    for (int c = 0; c < 4; ++c) {
        int i = c * 256 + l * 4;
        f32x4 wg = *reinterpret_cast<const f32x4*>(wv + i);
        f32x4 ss = *reinterpret_cast<const f32x4*>(src + i);
        acc += ss[0] * wg[0] + ss[1] * wg[1] + ss[2] * wg[2] + ss[3] * wg[3];
    }
    #pragma unroll
    for (int off = 32; off > 0; off >>= 1) acc += __shfl_xor(acc, off);
    __shared__ float red[4];
    if (l == 0) red[w] = acc;
    __syncthreads();
    if (t == 0) {
        float nm0 = tanhf(red[0] + bn[0]);
        float nm1 = tanhf(red[1] + bn[1]);
        float nm = nm0 - nm1;
        nm_f[b] = nm;
        out[BATCH + b] = nm;                                  // neuromodulator
        out[b] = 1.0f / (1.0f + __expf(-(red[2] + bc[0])));   // choice
        out[2 * BATCH + b] = red[3] + bv[0];                  // value
    }
    const size_t HID_OFF = (size_t)3 * BATCH + (size_t)BATCH * HDIM * HDIM;
    for (int i = t; i < HDIM; i += 256)
        out[HID_OFF + (size_t)b * HDIM + i] = hid_f[(b << 10) + i];
}

// K4: new_plastic = clip(plastic + nm[b]*tanh(pre[b,h]*emb[b,i])*10, -50, 50)
// REVERSE streaming order: k2 streamed plastic forward, so the L3 holds the
// tail; reading tail-first converts part of the fetch into L3 hits.
// Non-temporal stores keep the write stream from evicting those lines.
__global__ __launch_bounds__(256) void k4_update(
    const float* __restrict__ plastic, const float* __restrict__ emb_f,
    const float* __restrict__ pre_f, const float* __restrict__ nm_f,
    float* __restrict__ outp)
{
    const size_t NG = (size_t)BATCH * HDIM * HDIM / 4;
    size_t gid = (size_t)blockIdx.x * 256 + threadIdx.x;
    size_t idx = (NG - 1 - gid) * 4;
    int b   = (int)(idx >> 20);
    int rem = (int)(idx & 1048575u);
    int h   = rem >> 10;
    int i0  = rem & 1023;
    float nm  = nm_f[b];
    float pre = pre_f[(b << 10) + h];
    f32x4 p = *reinterpret_cast<const f32x4*>(plastic + idx);
    f32x4 e = *reinterpret_cast<const f32x4*>(emb_f + (b << 10) + i0);
    f32x4 o;
    #pragma unroll
    for (int j = 0; j < 4; ++j) {
        float heb = fast_tanh(pre * e[j]) * 10.0f;
        float v = fmaf(nm, heb, p[j]);
        o[j] = fminf(fmaxf(v, -50.0f), 50.0f);
    }
    __builtin_nontemporal_store(o, reinterpret_cast<f32x4*>(outp + idx));
}

extern "C" void kernel_launch(void* const* d_in, const int* in_sizes, int n_in,
                              void* d_out, int out_size, void* d_ws, size_t ws_size,
                              hipStream_t stream)
{
    const float* items   = (const float*)d_in[0];
    const float* plastic = (const float*)d_in[1];
    const float* reward  = (const float*)d_in[2];
    const float* W1 = (const float*)d_in[3];
    const float* b1 = (const float*)d_in[4];
    const float* W2 = (const float*)d_in[5];
    const float* b2 = (const float*)d_in[6];
    const float* W3 = (const float*)d_in[7];
    const float* b3 = (const float*)d_in[8];
    const float* Wc = (const float*)d_in[9];
    const float* bc = (const float*)d_in[10];
    const float* Wr = (const float*)d_in[11];
    const float* br = (const float*)d_in[12];
    const float* Wn = (const float*)d_in[13];
    const float* bn = (const float*)d_in[14];
    const float* alpha = (const float*)d_in[15];
    const float* Wv = (const float*)d_in[16];
    const float* bv = (const float*)d_in[17];

    float* ws    = (float*)d_ws;
    float* emb_f = ws;                // 131072 floats
    float* pre_f = ws + 131072;       // 131072
    float* hid_f = ws + 262144;       // 131072
    float* t3_f  = ws + 393216;       // 131072
    float* nm_f  = ws + 524288;       // 128

    float* out  = (float*)d_out;
    float* outp = out + 384;          // new_plastic after choice/nm/value

    k1_emb   <<<BATCH, 256, 0, stream>>>(items, W1, b1, emb_f);
    k2_hidden<<<(HDIM / 4) * (BATCH / BCHUNK), 256, 0, stream>>>(plastic, alpha, W2, b2, emb_f, pre_f, hid_f);
    k3a_t3   <<<(BATCH * HDIM) / 4, 256, 0, stream>>>(hid_f, reward, Wr, br, W3, b3, t3_f);
    k3b_heads<<<BATCH, 256, 0, stream>>>(t3_f, hid_f, Wn, bn, Wc, bc, Wv, bv, nm_f, out);
    k4_update<<<(size_t)(BATCH * HDIM) * HDIM / 1024, 256, 0, stream>>>(plastic, emb_f, pre_f, nm_f, outp);
}